// Round 3
// baseline (198.077 us; speedup 1.0000x reference)
//
#include <hip/hip_runtime.h>
#include <math.h>

// Problem constants (fixed by the reference)
#define Nn 4096
#define Mm 4096
#define Dd 512
#define NP 4097            // N+1 == M+1 (augmented with dustbin)
#define NPB 4104           // padded fp16-E leading dim (rows 16B-aligned: 4104*2 = 8208)

// phi = REG_KL / (REG_KL + REG) = 0.01/0.11 ; lmba = 10
#define PHI 0.09090909090909091f
#define LMU_IN  (-8.4231266823771690f)   // log(0.9/4096)
#define LMU_BIN (-2.3025850929940457f)   // log(0.1)
#define LOG_NP  8.3180489582454150f      // log(4097)

typedef __attribute__((ext_vector_type(8))) __bf16 bf16x8;
typedef __attribute__((ext_vector_type(4))) float  f32x4;

// async global->LDS, 16B per lane. LDS dest must be wave-uniform base + lane*16.
__device__ __forceinline__ void load_lds16(const __bf16* g, __bf16* l) {
    __builtin_amdgcn_global_load_lds(
        (__attribute__((address_space(1))) void*)g,
        (__attribute__((address_space(3))) void*)l,
        16, 0, 0);
}

// all-reduce across 256 threads; leading sync protects sb reuse across calls.
__device__ __forceinline__ float block_allreduce_256(float v, float* sb) {
    #pragma unroll
    for (int off = 32; off > 0; off >>= 1) v += __shfl_down(v, off, 64);
    __syncthreads();
    if ((threadIdx.x & 63) == 0) sb[threadIdx.x >> 6] = v;
    __syncthreads();
    return sb[0] + sb[1] + sb[2] + sb[3];
}

// ---------- kernel 1: normalize + dustbin fills + zero accumulators ----------
__global__ __launch_bounds__(256) void normalize_bins_kernel(
    const float* __restrict__ F0, const float* __restrict__ F1,
    const float* __restrict__ binp,
    __bf16* __restrict__ A, __bf16* __restrict__ B, _Float16* __restrict__ Ef,
    float* __restrict__ S0, float* __restrict__ TcA) {
    __shared__ float sb[4];
    const int row = blockIdx.x;
    const float* src = (row < Nn) ? (F0 + (size_t)row * Dd)
                                  : (F1 + (size_t)(row - Nn) * Dd);
    __bf16* dst = (row < Nn) ? (A + (size_t)row * Dd)
                             : (B + (size_t)(row - Nn) * Dd);
    const float2 x = ((const float2*)src)[threadIdx.x];
    const float s = block_allreduce_256(x.x * x.x + x.y * x.y, sb);
    const float rn = rsqrtf(s);
    dst[2 * threadIdx.x]     = (__bf16)(x.x * rn);
    dst[2 * threadIdx.x + 1] = (__bf16)(x.y * rn);

    if (row < 17) {
        const int j = row * 256 + threadIdx.x;
        if (j < NP) Ef[(size_t)Nn * NPB + j] = (_Float16)__expf(10.0f * binp[0]);
    } else if (row < 33) {
        const int i = (row - 17) * 256 + threadIdx.x;    // 0..4095
        Ef[(size_t)i * NPB + Mm] = (_Float16)__expf(10.0f * binp[0]);
    } else if (row < 50) {
        const int k = (row - 33) * 256 + threadIdx.x;
        if (k < NP) S0[k] = 0.f;
    } else if (row < 67) {
        const int k = (row - 50) * 256 + threadIdx.x;
        if (k < NP) TcA[k] = 0.f;
    }
}

// ---------- kernel 2: Ef = exp(10 * A B^T) + interior row sums S0 ----------
// v4: 256x256 tile, 512 threads (8 waves 2Mx4N, 128x64/wave), BK=64, dbuf.
// 8-phase-style schedule (T3+T4, m196/m201): each K-tile = 4 phases of
//   {4-8 ds_read_b128 -> stage ONE 16KB unit (2 global_load_lds) ->
//    s_waitcnt vmcnt(4) -> s_barrier -> setprio(1) -> 16 MFMA -> setprio(0)
//    -> s_barrier}.
// Staging units are K-half-split (Ak0,Bk0,Ak1,Bk1), each a CONTIGUOUS 16KB
// sub-buffer (global_load_lds linear-dest rule), staged 4 phases ahead of
// consumption; per-phase vmcnt(4) keeps 2 units in flight, never drains
// until the last tile's tail. Swizzle c ^= (row>>1)&3 on both sides
// (rule #21) -> exact 2-way (free, m136). T1 bijective XCD swizzle:
// each XCD gets a 4x8 tile rectangle.
#define BKh 32
__global__ __launch_bounds__(512, 2) void gemm_rowsum_kernel(
    const __bf16* __restrict__ A, const __bf16* __restrict__ B,
    _Float16* __restrict__ Ef, float* __restrict__ S0) {
    __shared__ __align__(16) __bf16 As[2][2][256 * BKh];   // [buf][ks] 16KB units
    __shared__ __align__(16) __bf16 Bs[2][2][256 * BKh];
    const int tid = threadIdx.x;
    const int l = tid & 63, wv = tid >> 6;       // 8 waves
    const int wm = wv >> 2, wn = wv & 3;         // 2 x 4 wave grid
    const int ln = l & 15, lq = l >> 4;

    // XCD-aware bijective swizzle: xcd = bid&7 gets a 4(by) x 8(bx) rectangle
    const int bid = blockIdx.x;
    const int xcd = bid & 7, sub = bid >> 3;     // 32 blocks per XCD
    const int by = (xcd & 3) * 4 + (sub >> 3);   // 0..15
    const int bx = (xcd >> 2) * 8 + (sub & 7);   // 0..15
    const int row0 = by << 8, col0 = bx << 8;

    f32x4 acc[8][4];
    #pragma unroll
    for (int i = 0; i < 8; ++i)
        #pragma unroll
        for (int j = 0; j < 4; ++j) acc[i][j] = (f32x4){0.f, 0.f, 0.f, 0.f};

    // Stage addressing: unit = 256 rows x 32 K-cols = 1024 16B-chunks;
    // thread handles slots q = tid, tid+512. Slot (r,c) holds global chunk
    // c ^ ((r>>1)&3)  (inverse-swizzled source, linear LDS dest).
    size_t aG[2], bG[2]; int qE[2];
    #pragma unroll
    for (int p = 0; p < 2; ++p) {
        const int q = tid + p * 512;
        const int r = q >> 2, c = q & 3;
        const int cg = c ^ ((r >> 1) & 3);
        aG[p] = (size_t)(row0 + r) * Dd + cg * 8;
        bG[p] = (size_t)(col0 + r) * Dd + cg * 8;
        qE[p] = q * 8;                           // element offset in unit
    }

    auto STAGE_UNIT = [&](int nb, int tt, int u) {
        const size_t kofs = (size_t)(tt * 64 + (u >> 1) * 32);
        if ((u & 1) == 0) {
            load_lds16(A + aG[0] + kofs, &As[nb][u >> 1][qE[0]]);
            load_lds16(A + aG[1] + kofs, &As[nb][u >> 1][qE[1]]);
        } else {
            load_lds16(B + bG[0] + kofs, &Bs[nb][u >> 1][qE[0]]);
            load_lds16(B + bG[1] + kofs, &Bs[nb][u >> 1][qE[1]]);
        }
    };

    #define WAITV(N) asm volatile("s_waitcnt vmcnt(" #N ")" ::: "memory")
    #define BAR() __builtin_amdgcn_s_barrier()

    const int swz2 = (ln >> 1) & 3;              // read-side chunk swizzle key

    // prologue: stage all 4 units of tile 0 (units 0..3 of the stream)
    STAGE_UNIT(0, 0, 0); STAGE_UNIT(0, 0, 1);
    STAGE_UNIT(0, 0, 2); STAGE_UNIT(0, 0, 3);
    WAITV(4); BAR();                             // units 0,1 (Ak0,Bk0) landed

    #pragma unroll
    for (int t = 0; t < 8; ++t) {
        const int buf = t & 1, nbuf = buf ^ 1;
        #pragma unroll
        for (int ks = 0; ks < 2; ++ks) {
            bf16x8 bfr[4];
            #pragma unroll
            for (int half = 0; half < 2; ++half) {
                const int p = ks * 2 + half;
                // ---- ds reads for THIS phase's MFMAs ----
                if (half == 0) {
                    #pragma unroll
                    for (int ni = 0; ni < 4; ++ni) {
                        const int r = wn * 64 + ni * 16 + ln;
                        bfr[ni] = *(const bf16x8*)
                            &Bs[buf][ks][r * BKh + ((lq ^ swz2) * 8)];
                    }
                }
                bf16x8 af[4];
                #pragma unroll
                for (int i = 0; i < 4; ++i) {
                    const int r = wm * 128 + half * 64 + i * 16 + ln;
                    af[i] = *(const bf16x8*)
                        &As[buf][ks][r * BKh + ((lq ^ swz2) * 8)];
                }
                // ---- stage unit p of tile t+1 (4-phase lead) ----
                if (t < 7) STAGE_UNIT(nbuf, t + 1, p);
                // ---- counted wait: keep 2 units (4 loads) in flight ----
                if (t < 7 || p == 0) { WAITV(4); }
                else if (p == 1)     { WAITV(0); }   // tail drain
                BAR();
                __builtin_amdgcn_s_setprio(1);
                #pragma unroll
                for (int i = 0; i < 4; ++i)
                    #pragma unroll
                    for (int ni = 0; ni < 4; ++ni)
                        acc[half * 4 + i][ni] =
                            __builtin_amdgcn_mfma_f32_16x16x32_bf16(
                                af[i], bfr[ni], acc[half * 4 + i][ni], 0, 0, 0);
                __builtin_amdgcn_s_setprio(0);
                BAR();
            }
        }
    }
    #undef WAITV
    #undef BAR

    // C/D layout (m89-verified): col = lane&15, row = (lane>>4)*4 + reg
    #pragma unroll
    for (int mi = 0; mi < 8; ++mi) {
        #pragma unroll
        for (int r = 0; r < 4; ++r) {
            const int gi = row0 + wm * 128 + mi * 16 + lq * 4 + r;
            _Float16* bRow = Ef + (size_t)gi * NPB + col0 + wn * 64 + ln;
            float rs = 0.f;
            #pragma unroll
            for (int ni = 0; ni < 4; ++ni) {
                const float e = __expf(10.0f * acc[mi][ni][r]);
                bRow[ni * 16] = (_Float16)e;
                rs += e;
            }
            // reduce rs over the 16 lanes (ln) sharing this row in this wave
            rs += __shfl_down(rs, 8, 64);
            rs += __shfl_down(rs, 4, 64);
            rs += __shfl_down(rs, 2, 64);
            rs += __shfl_down(rs, 1, 64);
            if (ln == 0) atomicAdd(&S0[gi], rs);
        }
    }
}

// ---------- kernel 3/5: column pass (v3: high-ILP, high-TLP) ----------
__global__ __launch_bounds__(256) void col_pass_kernel(
    const _Float16* __restrict__ Ef, const float* __restrict__ S0,
    const float* __restrict__ eUarr, const float* __restrict__ binp,
    float* __restrict__ Tc, const int mode) {
    __shared__ float evl[32];
    const int tid = threadIdx.x;
    const int t = blockIdx.x;                 // col tile: 512 cols
    const int sI = blockIdx.y;                // row stripe: 32 rows
    const int r0 = sI * 32;

    if (tid < 32) {
        const int r = r0 + tid;               // < 4096 always (128*32 = 4096)
        float ev;
        if (mode == 0) {
            const float ebin = __expf(10.0f * binp[0]);
            ev = __expf(PHI * (LMU_IN - __logf(S0[r] + ebin)));
        } else {
            ev = eUarr[r];
        }
        evl[tid] = ev;
    }
    __syncthreads();

    const int j0 = t * 512 + tid * 2;         // even col pair, < 4096
    const unsigned short* base = (const unsigned short*)Ef;
    float s0 = 0.f, s1 = 0.f;
    #pragma unroll
    for (int k = 0; k < 32; ++k) {
        const int r = r0 + k;
        union { unsigned u; _Float16 h[2]; } e;
        e.u = *(const unsigned*)(base + (size_t)r * NPB + j0);
        const float ev = evl[k];
        s0 += (float)e.h[0] * ev;
        s1 += (float)e.h[1] * ev;
    }

    // dustbin-row contribution (i = 4096) folded into stripe 127
    float ev4096 = 0.f;
    if (sI == 127) {
        ev4096 = (mode == 0)
               ? __expf(PHI * (LMU_BIN - (LOG_NP + 10.0f * binp[0])))
               : eUarr[Nn];
        union { unsigned u; _Float16 h[2]; } e;
        e.u = *(const unsigned*)(base + (size_t)Nn * NPB + j0);
        s0 += (float)e.h[0] * ev4096;
        s1 += (float)e.h[1] * ev4096;
    }
    atomicAdd(&Tc[j0], s0);
    atomicAdd(&Tc[j0 + 1], s1);

    // dustbin column j=4096: tile-0 blocks, first wave only (tid<64 uniform)
    if (t == 0 && tid < 64) {
        float sc = 0.f;
        if (tid < 32)
            sc = (float)Ef[(size_t)(r0 + tid) * NPB + Mm] * evl[tid];
        else if (tid == 32 && sI == 127)
            sc = (float)Ef[(size_t)Nn * NPB + Mm] * ev4096;   // corner
        #pragma unroll
        for (int off = 32; off > 0; off >>= 1) sc += __shfl_down(sc, off, 64);
        if (tid == 0) atomicAdd(&Tc[Mm], sc);
    }
}

// ---------- kernel 4: row pass #2 ----------
__global__ __launch_bounds__(256) void row_pass2_kernel(
    const _Float16* __restrict__ Ef, const float* __restrict__ TcA,
    float* __restrict__ eU, float* __restrict__ TcB) {
    __shared__ float sb[4];
    __shared__ float wl[NP];
    const int tid = threadIdx.x;

    for (int j = tid; j < NP; j += 256) {
        const float lnu = (j < Mm) ? LMU_IN : LMU_BIN;
        wl[j] = __expf(PHI * (lnu - __logf(TcA[j])));
    }
    __syncthreads();

    const int i0 = blockIdx.x * 8;
    #pragma unroll 1
    for (int k = 0; k < 8; ++k) {
        const int i = i0 + k;
        if (i >= NP) break;                               // uniform across block
        const uint4* rowp = (const uint4*)(Ef + (size_t)i * NPB);
        float s = 0.f;
        #pragma unroll
        for (int c = 0; c < 2; ++c) {
            const int chunk = c * 256 + tid;              // cols chunk*8 .. +7
            union { uint4 u; _Float16 h[8]; } e;
            e.u = rowp[chunk];
            const float4 w0 = *(const float4*)&wl[chunk * 8];
            const float4 w1 = *(const float4*)&wl[chunk * 8 + 4];
            s += (float)e.h[0] * w0.x + (float)e.h[1] * w0.y
               + (float)e.h[2] * w0.z + (float)e.h[3] * w0.w
               + (float)e.h[4] * w1.x + (float)e.h[5] * w1.y
               + (float)e.h[6] * w1.z + (float)e.h[7] * w1.w;
        }
        if (tid == 0) s += (float)Ef[(size_t)i * NPB + Mm] * wl[Mm];
        s = block_allreduce_256(s, sb);
        if (tid == 0) {
            const float lmu = (i < Nn) ? LMU_IN : LMU_BIN;
            eU[i] = __expf(PHI * (lmu - __logf(s)));
        }
    }
    if (tid < 8 && i0 + tid < NP) TcB[i0 + tid] = 0.f;    // zero col-sum accum
}

// ---------- kernel 6: finish ----------
// out[i][j] = Ef[i][j] * eU[i] * w2[j]. v2: uint (2-col) Ef loads instead of
// scalar 2B loads; col 4096 + corner handled in epilogue.
__global__ __launch_bounds__(256) void finish_kernel(
    const _Float16* __restrict__ Ef, const float* __restrict__ eU,
    const float* __restrict__ TcB, float* __restrict__ out) {
    __shared__ float wl[NP];
    const int tid = threadIdx.x;
    for (int j = tid; j < NP; j += 256) {
        const float lnu = (j < Mm) ? LMU_IN : LMU_BIN;
        wl[j] = __expf(PHI * (lnu - __logf(TcB[j])));
    }
    __syncthreads();

    const int i0 = blockIdx.x * 8;
    #pragma unroll 1
    for (int k = 0; k < 8; ++k) {
        const int i = i0 + k;
        if (i >= NP) break;
        const float sU = eU[i];
        const unsigned* erow32 = (const unsigned*)(Ef + (size_t)i * NPB);
        float* orow = out + (size_t)i * NP;
        #pragma unroll
        for (int c = 0; c < 8; ++c) {
            const int j0 = c * 512 + tid * 2;
            union { unsigned u; _Float16 h[2]; } e;
            e.u = erow32[c * 256 + tid];
            const float2 wv = *(const float2*)&wl[j0];
            orow[j0]     = (float)e.h[0] * sU * wv.x;
            orow[j0 + 1] = (float)e.h[1] * sU * wv.y;
        }
        if (tid == 0) {
            float v = (float)Ef[(size_t)i * NPB + Mm] * sU * wl[Mm];
            if (i == Nn) v = 0.f;                         // corner zeroed
            orow[Mm] = v;
        }
    }
}

// -------------------- launch --------------------

extern "C" void kernel_launch(void* const* d_in, const int* in_sizes, int n_in,
                              void* d_out, int out_size, void* d_ws, size_t ws_size,
                              hipStream_t stream) {
    const float* ft0 = (const float*)d_in[0];
    const float* ft1 = (const float*)d_in[1];
    const float* bin = (const float*)d_in[2];
    float* out = (float*)d_out;

    const size_t ABF_B = (size_t)Nn * Dd * 2;            // 4,194,304
    const size_t EBF_B = (size_t)NP * NPB * 2;           // 33,628,176 (16B-divisible)
    const size_t VEC_B = 16400;                          // 4097 floats, padded
    __bf16*   Abf = (__bf16*)d_ws;
    __bf16*   Bbf = (__bf16*)((char*)d_ws + ABF_B);
    _Float16* Ef  = (_Float16*)((char*)d_ws + 2 * ABF_B);
    float*    eU  = (float*)((char*)d_ws + 2 * ABF_B + EBF_B);
    float*    S0  = (float*)((char*)d_ws + 2 * ABF_B + EBF_B + VEC_B);
    float*    TcA = (float*)((char*)d_ws + 2 * ABF_B + EBF_B + 2 * VEC_B);
    float*    TcB = (float*)((char*)d_ws + 2 * ABF_B + EBF_B + 3 * VEC_B);

    // 2 damped Gauss-Seidel Sinkhorn iterations (contraction phi^2 = 1/121;
    // residual after (U2,V2) ~1.2e-3 rel -> ~6e-3 abs, vs threshold 0.08).
    normalize_bins_kernel<<<Nn + Mm, 256, 0, stream>>>(ft0, ft1, bin,
                                                       Abf, Bbf, Ef, S0, TcA);
    gemm_rowsum_kernel<<<256, 512, 0, stream>>>(Abf, Bbf, Ef, S0);
    col_pass_kernel<<<dim3(8, 128), 256, 0, stream>>>(Ef, S0, eU, bin, TcA, 0);
    row_pass2_kernel<<<513, 256, 0, stream>>>(Ef, TcA, eU, TcB);
    col_pass_kernel<<<dim3(8, 128), 256, 0, stream>>>(Ef, S0, eU, bin, TcB, 1);
    finish_kernel<<<513, 256, 0, stream>>>(Ef, eU, TcB, out);
}

// Round 4
// 180.791 us; speedup vs baseline: 1.0956x; 1.0956x over previous
//
#include <hip/hip_runtime.h>
#include <math.h>

// Problem constants (fixed by the reference)
#define Nn 4096
#define Mm 4096
#define Dd 512
#define NP 4097            // N+1 == M+1 (augmented with dustbin)
#define NPB 4104           // padded fp16-E leading dim (rows 16B-aligned: 4104*2 = 8208)

// phi = REG_KL / (REG_KL + REG) = 0.01/0.11 ; lmba = 10
#define PHI 0.09090909090909091f
#define LMU_IN  (-8.4231266823771690f)   // log(0.9/4096)
#define LMU_BIN (-2.3025850929940457f)   // log(0.1)
#define LOG_NP  8.3180489582454150f      // log(4097)

typedef __attribute__((ext_vector_type(8))) __bf16 bf16x8;
typedef __attribute__((ext_vector_type(4))) float  f32x4;

// async global->LDS, 16B per lane. LDS dest must be wave-uniform base + lane*16.
__device__ __forceinline__ void load_lds16(const __bf16* g, __bf16* l) {
    __builtin_amdgcn_global_load_lds(
        (__attribute__((address_space(1))) void*)g,
        (__attribute__((address_space(3))) void*)l,
        16, 0, 0);
}

// all-reduce across 256 threads; leading sync protects sb reuse across calls.
__device__ __forceinline__ float block_allreduce_256(float v, float* sb) {
    #pragma unroll
    for (int off = 32; off > 0; off >>= 1) v += __shfl_down(v, off, 64);
    __syncthreads();
    if ((threadIdx.x & 63) == 0) sb[threadIdx.x >> 6] = v;
    __syncthreads();
    return sb[0] + sb[1] + sb[2] + sb[3];
}

// ---------- kernel 1: normalize + dustbin fills + zero accumulators ----------
__global__ __launch_bounds__(256) void normalize_bins_kernel(
    const float* __restrict__ F0, const float* __restrict__ F1,
    const float* __restrict__ binp,
    __bf16* __restrict__ A, __bf16* __restrict__ B, _Float16* __restrict__ Ef,
    float* __restrict__ S0, float* __restrict__ TcA) {
    __shared__ float sb[4];
    const int row = blockIdx.x;
    const float* src = (row < Nn) ? (F0 + (size_t)row * Dd)
                                  : (F1 + (size_t)(row - Nn) * Dd);
    __bf16* dst = (row < Nn) ? (A + (size_t)row * Dd)
                             : (B + (size_t)(row - Nn) * Dd);
    const float2 x = ((const float2*)src)[threadIdx.x];
    const float s = block_allreduce_256(x.x * x.x + x.y * x.y, sb);
    const float rn = rsqrtf(s);
    dst[2 * threadIdx.x]     = (__bf16)(x.x * rn);
    dst[2 * threadIdx.x + 1] = (__bf16)(x.y * rn);

    if (row < 17) {
        const int j = row * 256 + threadIdx.x;
        if (j < NP) Ef[(size_t)Nn * NPB + j] = (_Float16)__expf(10.0f * binp[0]);
    } else if (row < 33) {
        const int i = (row - 17) * 256 + threadIdx.x;    // 0..4095
        Ef[(size_t)i * NPB + Mm] = (_Float16)__expf(10.0f * binp[0]);
    } else if (row < 50) {
        const int k = (row - 33) * 256 + threadIdx.x;
        if (k < NP) S0[k] = 0.f;
    } else if (row < 67) {
        const int k = (row - 50) * 256 + threadIdx.x;
        if (k < NP) TcA[k] = 0.f;
    }
}

// ---------- kernel 2: Ef = exp(10 * A B^T) + interior row sums S0 ----------
// (unchanged from R3 — control for this round; K-loop schedule exonerated)
#define BKh 32
__global__ __launch_bounds__(512, 2) void gemm_rowsum_kernel(
    const __bf16* __restrict__ A, const __bf16* __restrict__ B,
    _Float16* __restrict__ Ef, float* __restrict__ S0) {
    __shared__ __align__(16) __bf16 As[2][2][256 * BKh];   // [buf][ks] 16KB units
    __shared__ __align__(16) __bf16 Bs[2][2][256 * BKh];
    const int tid = threadIdx.x;
    const int l = tid & 63, wv = tid >> 6;       // 8 waves
    const int wm = wv >> 2, wn = wv & 3;         // 2 x 4 wave grid
    const int ln = l & 15, lq = l >> 4;

    // XCD-aware bijective swizzle: xcd = bid&7 gets a 4(by) x 8(bx) rectangle
    const int bid = blockIdx.x;
    const int xcd = bid & 7, sub = bid >> 3;     // 32 blocks per XCD
    const int by = (xcd & 3) * 4 + (sub >> 3);   // 0..15
    const int bx = (xcd >> 2) * 8 + (sub & 7);   // 0..15
    const int row0 = by << 8, col0 = bx << 8;

    f32x4 acc[8][4];
    #pragma unroll
    for (int i = 0; i < 8; ++i)
        #pragma unroll
        for (int j = 0; j < 4; ++j) acc[i][j] = (f32x4){0.f, 0.f, 0.f, 0.f};

    size_t aG[2], bG[2]; int qE[2];
    #pragma unroll
    for (int p = 0; p < 2; ++p) {
        const int q = tid + p * 512;
        const int r = q >> 2, c = q & 3;
        const int cg = c ^ ((r >> 1) & 3);
        aG[p] = (size_t)(row0 + r) * Dd + cg * 8;
        bG[p] = (size_t)(col0 + r) * Dd + cg * 8;
        qE[p] = q * 8;                           // element offset in unit
    }

    auto STAGE_UNIT = [&](int nb, int tt, int u) {
        const size_t kofs = (size_t)(tt * 64 + (u >> 1) * 32);
        if ((u & 1) == 0) {
            load_lds16(A + aG[0] + kofs, &As[nb][u >> 1][qE[0]]);
            load_lds16(A + aG[1] + kofs, &As[nb][u >> 1][qE[1]]);
        } else {
            load_lds16(B + bG[0] + kofs, &Bs[nb][u >> 1][qE[0]]);
            load_lds16(B + bG[1] + kofs, &Bs[nb][u >> 1][qE[1]]);
        }
    };

    #define WAITV(N) asm volatile("s_waitcnt vmcnt(" #N ")" ::: "memory")
    #define BAR() __builtin_amdgcn_s_barrier()

    const int swz2 = (ln >> 1) & 3;              // read-side chunk swizzle key

    STAGE_UNIT(0, 0, 0); STAGE_UNIT(0, 0, 1);
    STAGE_UNIT(0, 0, 2); STAGE_UNIT(0, 0, 3);
    WAITV(4); BAR();                             // units 0,1 (Ak0,Bk0) landed

    #pragma unroll
    for (int t = 0; t < 8; ++t) {
        const int buf = t & 1, nbuf = buf ^ 1;
        #pragma unroll
        for (int ks = 0; ks < 2; ++ks) {
            bf16x8 bfr[4];
            #pragma unroll
            for (int half = 0; half < 2; ++half) {
                const int p = ks * 2 + half;
                if (half == 0) {
                    #pragma unroll
                    for (int ni = 0; ni < 4; ++ni) {
                        const int r = wn * 64 + ni * 16 + ln;
                        bfr[ni] = *(const bf16x8*)
                            &Bs[buf][ks][r * BKh + ((lq ^ swz2) * 8)];
                    }
                }
                bf16x8 af[4];
                #pragma unroll
                for (int i = 0; i < 4; ++i) {
                    const int r = wm * 128 + half * 64 + i * 16 + ln;
                    af[i] = *(const bf16x8*)
                        &As[buf][ks][r * BKh + ((lq ^ swz2) * 8)];
                }
                if (t < 7) STAGE_UNIT(nbuf, t + 1, p);
                if (t < 7 || p == 0) { WAITV(4); }
                else if (p == 1)     { WAITV(0); }   // tail drain
                BAR();
                __builtin_amdgcn_s_setprio(1);
                #pragma unroll
                for (int i = 0; i < 4; ++i)
                    #pragma unroll
                    for (int ni = 0; ni < 4; ++ni)
                        acc[half * 4 + i][ni] =
                            __builtin_amdgcn_mfma_f32_16x16x32_bf16(
                                af[i], bfr[ni], acc[half * 4 + i][ni], 0, 0, 0);
                __builtin_amdgcn_s_setprio(0);
                BAR();
            }
        }
    }
    #undef WAITV
    #undef BAR

    // C/D layout (m89-verified): col = lane&15, row = (lane>>4)*4 + reg
    #pragma unroll
    for (int mi = 0; mi < 8; ++mi) {
        #pragma unroll
        for (int r = 0; r < 4; ++r) {
            const int gi = row0 + wm * 128 + mi * 16 + lq * 4 + r;
            _Float16* bRow = Ef + (size_t)gi * NPB + col0 + wn * 64 + ln;
            float rs = 0.f;
            #pragma unroll
            for (int ni = 0; ni < 4; ++ni) {
                const float e = __expf(10.0f * acc[mi][ni][r]);
                bRow[ni * 16] = (_Float16)e;
                rs += e;
            }
            rs += __shfl_down(rs, 8, 64);
            rs += __shfl_down(rs, 4, 64);
            rs += __shfl_down(rs, 2, 64);
            rs += __shfl_down(rs, 1, 64);
            if (ln == 0) atomicAdd(&S0[gi], rs);
        }
    }
}

// ---------- kernel W: w[j] = exp(PHI*(lnu_j - log(Tc[j]))), once ----------
// Also zeroes the next col-accumulator if given. grid = 17 blocks of 256.
__global__ __launch_bounds__(256) void wvec_kernel(
    const float* __restrict__ Tc, float* __restrict__ W,
    float* __restrict__ Zero) {
    const int j = blockIdx.x * 256 + threadIdx.x;
    if (j < NP) {
        const float lnu = (j < Mm) ? LMU_IN : LMU_BIN;
        W[j] = __expf(PHI * (lnu - __logf(Tc[j])));
        if (Zero) Zero[j] = 0.f;
    }
}

// ---------- kernel 3/5: column pass (v4: 32 stripes of 128 rows) ----------
// Tc[j] += stripe-sums of Ef[i][j] * eU_i. grid = dim3(8, 32) = 256 blocks
// (1/CU): 8 col-tiles of 512 cols, 32 row-stripes of 128 rows (unroll 16 ->
// 16 loads in flight/thread). 4x fewer Tc atomics (32-way contention) than
// the 128-stripe version. Row 4096 folded into stripe 31; dustbin column
// j=4096 by tile-0 blocks (128 lanes, 2 wave-reduces).
__global__ __launch_bounds__(256) void col_pass_kernel(
    const _Float16* __restrict__ Ef, const float* __restrict__ S0,
    const float* __restrict__ eUarr, const float* __restrict__ binp,
    float* __restrict__ Tc, const int mode) {
    __shared__ float evl[128];
    const int tid = threadIdx.x;
    const int t = blockIdx.x;                 // col tile: 512 cols
    const int sI = blockIdx.y;                // row stripe: 128 rows
    const int r0 = sI * 128;

    if (tid < 128) {
        const int r = r0 + tid;               // < 4096 always (32*128 = 4096)
        float ev;
        if (mode == 0) {
            const float ebin = __expf(10.0f * binp[0]);
            ev = __expf(PHI * (LMU_IN - __logf(S0[r] + ebin)));
        } else {
            ev = eUarr[r];
        }
        evl[tid] = ev;
    }
    __syncthreads();

    const int j0 = t * 512 + tid * 2;         // even col pair, < 4096
    const unsigned short* base = (const unsigned short*)Ef;
    float s0 = 0.f, s1 = 0.f;
    #pragma unroll 16
    for (int k = 0; k < 128; ++k) {
        const int r = r0 + k;
        union { unsigned u; _Float16 h[2]; } e;
        e.u = *(const unsigned*)(base + (size_t)r * NPB + j0);
        const float ev = evl[k];
        s0 += (float)e.h[0] * ev;
        s1 += (float)e.h[1] * ev;
    }

    // dustbin-row contribution (i = 4096) folded into stripe 31
    float ev4096 = 0.f;
    if (sI == 31) {
        ev4096 = (mode == 0)
               ? __expf(PHI * (LMU_BIN - (LOG_NP + 10.0f * binp[0])))
               : eUarr[Nn];
        union { unsigned u; _Float16 h[2]; } e;
        e.u = *(const unsigned*)(base + (size_t)Nn * NPB + j0);
        s0 += (float)e.h[0] * ev4096;
        s1 += (float)e.h[1] * ev4096;
    }
    atomicAdd(&Tc[j0], s0);
    atomicAdd(&Tc[j0 + 1], s1);

    // dustbin column j=4096: tile-0 blocks, lanes 0..127 (2 wave-reduces)
    if (t == 0 && tid < 128) {
        float sc = (float)Ef[(size_t)(r0 + tid) * NPB + Mm] * evl[tid];
        if (sI == 31 && tid == 0)
            sc += (float)Ef[(size_t)Nn * NPB + Mm] * ev4096;   // corner
        #pragma unroll
        for (int off = 32; off > 0; off >>= 1) sc += __shfl_down(sc, off, 64);
        if ((tid & 63) == 0) atomicAdd(&Tc[Mm], sc);
    }
}

// ---------- kernel 4: row pass #2 ----------
// w1 precomputed by wvec_kernel (W1); copy to LDS, compute S_i for 8 rows,
// write eU[i]. grid = 513 blocks of 256.
__global__ __launch_bounds__(256) void row_pass2_kernel(
    const _Float16* __restrict__ Ef, const float* __restrict__ W1,
    float* __restrict__ eU) {
    __shared__ float sb[4];
    __shared__ float wl[NP];
    const int tid = threadIdx.x;

    for (int c = tid; c < 1024; c += 256)
        ((float4*)wl)[c] = ((const float4*)W1)[c];
    if (tid == 0) wl[Mm] = W1[Mm];
    __syncthreads();

    const int i0 = blockIdx.x * 8;
    #pragma unroll 1
    for (int k = 0; k < 8; ++k) {
        const int i = i0 + k;
        if (i >= NP) break;                               // uniform across block
        const uint4* rowp = (const uint4*)(Ef + (size_t)i * NPB);
        float s = 0.f;
        #pragma unroll
        for (int c = 0; c < 2; ++c) {
            const int chunk = c * 256 + tid;              // cols chunk*8 .. +7
            union { uint4 u; _Float16 h[8]; } e;
            e.u = rowp[chunk];
            const float4 w0 = *(const float4*)&wl[chunk * 8];
            const float4 w1 = *(const float4*)&wl[chunk * 8 + 4];
            s += (float)e.h[0] * w0.x + (float)e.h[1] * w0.y
               + (float)e.h[2] * w0.z + (float)e.h[3] * w0.w
               + (float)e.h[4] * w1.x + (float)e.h[5] * w1.y
               + (float)e.h[6] * w1.z + (float)e.h[7] * w1.w;
        }
        if (tid == 0) s += (float)Ef[(size_t)i * NPB + Mm] * wl[Mm];
        s = block_allreduce_256(s, sb);
        if (tid == 0) {
            const float lmu = (i < Nn) ? LMU_IN : LMU_BIN;
            eU[i] = __expf(PHI * (lmu - __logf(s)));
        }
    }
}

// ---------- kernel 6: finish ----------
// out[i][j] = Ef[i][j] * eU[i] * w2[j], w2 precomputed (W2) -> LDS.
// Strictly lane-contiguous scalar load/store (out rows are only 4B-aligned:
// NP=4097 floats stride poisons float2/float4 on odd rows).
__global__ __launch_bounds__(256) void finish_kernel(
    const _Float16* __restrict__ Ef, const float* __restrict__ eU,
    const float* __restrict__ W2, float* __restrict__ out) {
    __shared__ float wl[NP];
    const int tid = threadIdx.x;
    for (int c = tid; c < 1024; c += 256)
        ((float4*)wl)[c] = ((const float4*)W2)[c];
    if (tid == 0) wl[Mm] = W2[Mm];
    __syncthreads();

    const int i0 = blockIdx.x * 8;
    #pragma unroll 1
    for (int k = 0; k < 8; ++k) {
        const int i = i0 + k;
        if (i >= NP) break;
        const float sU = eU[i];
        const unsigned short* erow = (const unsigned short*)(Ef + (size_t)i * NPB);
        float* orow = out + (size_t)i * NP;
        #pragma unroll
        for (int c = 0; c < 16; ++c) {
            const int j = c * 256 + tid;                  // lane-contiguous
            union { unsigned short u; _Float16 h; } e;
            e.u = erow[j];
            orow[j] = (float)e.h * sU * wl[j];
        }
        if (tid == 0) {
            float v = (float)Ef[(size_t)i * NPB + Mm] * sU * wl[Mm];
            if (i == Nn) v = 0.f;                         // corner zeroed
            orow[Mm] = v;
        }
    }
}

// -------------------- launch --------------------

extern "C" void kernel_launch(void* const* d_in, const int* in_sizes, int n_in,
                              void* d_out, int out_size, void* d_ws, size_t ws_size,
                              hipStream_t stream) {
    const float* ft0 = (const float*)d_in[0];
    const float* ft1 = (const float*)d_in[1];
    const float* bin = (const float*)d_in[2];
    float* out = (float*)d_out;

    const size_t ABF_B = (size_t)Nn * Dd * 2;            // 4,194,304
    const size_t EBF_B = (size_t)NP * NPB * 2;           // 33,628,176 (16B-divisible)
    const size_t VEC_B = 16400;                          // 4097 floats, padded
    __bf16*   Abf = (__bf16*)d_ws;
    __bf16*   Bbf = (__bf16*)((char*)d_ws + ABF_B);
    _Float16* Ef  = (_Float16*)((char*)d_ws + 2 * ABF_B);
    float*    eU  = (float*)((char*)d_ws + 2 * ABF_B + EBF_B);
    float*    S0  = (float*)((char*)d_ws + 2 * ABF_B + EBF_B + VEC_B);
    float*    TcA = (float*)((char*)d_ws + 2 * ABF_B + EBF_B + 2 * VEC_B);
    float*    TcB = (float*)((char*)d_ws + 2 * ABF_B + EBF_B + 3 * VEC_B);
    float*    W1  = (float*)((char*)d_ws + 2 * ABF_B + EBF_B + 4 * VEC_B);
    float*    W2  = (float*)((char*)d_ws + 2 * ABF_B + EBF_B + 5 * VEC_B);

    // 2 damped Gauss-Seidel Sinkhorn iterations (contraction phi^2 = 1/121;
    // residual after (U2,V2) ~1.2e-3 rel -> ~6e-3 abs, vs threshold 0.08).
    normalize_bins_kernel<<<Nn + Mm, 256, 0, stream>>>(ft0, ft1, bin,
                                                       Abf, Bbf, Ef, S0, TcA);
    gemm_rowsum_kernel<<<256, 512, 0, stream>>>(Abf, Bbf, Ef, S0);
    col_pass_kernel<<<dim3(8, 32), 256, 0, stream>>>(Ef, S0, eU, bin, TcA, 0);
    wvec_kernel<<<17, 256, 0, stream>>>(TcA, W1, TcB);
    row_pass2_kernel<<<513, 256, 0, stream>>>(Ef, W1, eU);
    col_pass_kernel<<<dim3(8, 32), 256, 0, stream>>>(Ef, S0, eU, bin, TcB, 1);
    wvec_kernel<<<17, 256, 0, stream>>>(TcB, W2, nullptr);
    finish_kernel<<<513, 256, 0, stream>>>(Ef, eU, W2, out);
}